// Round 12
// baseline (142.624 us; speedup 1.0000x reference)
//
#include <hip/hip_runtime.h>

// R12: ATTRIBUTION ROUND. Real pipeline = R11 (best known: k_fused + k_outproj).
// Appended: 4 probe dispatches that decompose k_fused's 46us wall with
// per-dispatch rocprof counters. All probes are deterministic and output-safe:
// kp_A writes ws scratch; kp_AB rewrites outp with identical values (after
// k_outproj consumed it); kp_C<1> rewrites attn with identical values;
// kp_C<0> is asm-sunk (no DCE, no stores).
// B=32 T=64 F=128 H=8 NH=4 HD=2 HID=32. All f32.

namespace {
constexpr int Bb = 32, Tt = 64, Ff = 128, Hh = 8, HIDh = 32;
constexpr int G3H = 24;
constexpr float L2E = 1.44269504088896340736f;
// k_fused LDS (floats):
constexpr int XPS  = 0;                    // xp [4 f][65 t]
constexpr int HOUT = 260;                  // h  [4 f][8 j][65 t]
constexpr int OCT  = 2340;                 // q/ctx/o8 [4 f][64 t][10]
constexpr int KV   = 4900;                 // per wave: kk0|kk1|vv0|vv1 [4][68]
constexpr int SM_SIZE = KV + 4 * 1088;     // 9252 floats = 37.0 KB
// kp_C LDS: OCT2 [4][640] then KV2 [4][1088]
constexpr int OCT2 = 0, KV2 = 2560;
constexpr int SM_C = KV2 + 4 * 1088;       // 6912 floats = 27.6 KB
}

__device__ __forceinline__ float rcp_(float x) {
#if __has_builtin(__builtin_amdgcn_rcpf)
  return __builtin_amdgcn_rcpf(x);
#else
  return 1.0f / x;
#endif
}
__device__ __forceinline__ float exp2_(float x) {
#if __has_builtin(__builtin_amdgcn_exp2f)
  return __builtin_amdgcn_exp2f(x);
#else
  return exp2f(x);
#endif
}

#define MHA_STEP(K0C, K1C, V0C, V1C)                         \
  {                                                          \
    _Pragma("unroll") for (int i = 0; i < 4; ++i) {          \
      float s = fmaf(q0[i], K0C, q1[i] * K1C);               \
      float p = exp2_(s);                                    \
      ps[i] += p;                                            \
      c0[i] = fmaf(p, V0C, c0[i]);                           \
      c1[i] = fmaf(p, V1C, c1[i]);                           \
    }                                                        \
  }

// ================= real K1: R11 verbatim =================
__global__ __launch_bounds__(256, 4) void k_fused(
    const float* __restrict__ x, const float* __restrict__ Wp, const float* __restrict__ bp,
    const float* __restrict__ W_ih, const float* __restrict__ b_ih,
    const float* __restrict__ W_hh, const float* __restrict__ b_hh,
    const float* __restrict__ in_w, const float* __restrict__ in_b,
    const float* __restrict__ ow, const float* __restrict__ ob,
    float* __restrict__ outp, float* __restrict__ attn) {
  __shared__ float smem[SM_SIZE];
  const int tid = threadIdx.x;
  const int t = tid & 63;
  const int w = tid >> 6;
  const int blk = blockIdx.x;
  const int b = blk >> 5;
  const int f0 = (blk & 31) * 4;

  {
    const int f = f0 + w;
    const float4* xr = (const float4*)(x + (b * Tt + t) * Ff);
    const float4* wr = (const float4*)(Wp + f * Ff);
    float acc = bp[f];
#pragma unroll 8
    for (int k = 0; k < Ff / 4; ++k) {
      float4 xv = xr[k], wv = wr[k];
      acc = fmaf(xv.x, wv.x, acc); acc = fmaf(xv.y, wv.y, acc);
      acc = fmaf(xv.z, wv.z, acc); acc = fmaf(xv.w, wv.w, acc);
    }
    smem[XPS + w * 65 + t] = acc;
  }
  __syncthreads();

  if (tid < 32) {
    __builtin_amdgcn_s_setprio(1);
    const int g = t >> 3, j = t & 7;
    const int f = f0 + g;
    const float* wb = W_hh + (f * G3H + j) * Hh;
    const float nL = -L2E, S2 = 2.0f * L2E;
    float w0s[8], w1s[8], w2s[8];
#pragma unroll
    for (int h = 0; h < 8; ++h) {
      w0s[h] = wb[h] * nL;
      w1s[h] = wb[64 + h] * nL;
      w2s[h] = wb[128 + h] * S2;
    }
    const float wi0s = W_ih[f * G3H + j] * nL;
    const float wi1s = W_ih[f * G3H + 8 + j] * nL;
    const float wi2s = W_ih[f * G3H + 16 + j] * S2;
    const float bias_r = (b_ih[f * G3H + j] + b_hh[f * G3H + j]) * nL;
    const float bias_z = (b_ih[f * G3H + 8 + j] + b_hh[f * G3H + 8 + j]) * nL;
    const float bi2s = b_ih[f * G3H + 16 + j] * S2;
    const float bh2s = b_hh[f * G3H + 16 + j] * S2;
    float hall[8];
#pragma unroll
    for (int h = 0; h < 8; ++h) hall[h] = 0.f;
    float h_own = 0.f;
    const int base = t & 56;
    float* hdst = &smem[HOUT + g * 520 + j * 65];
    const float* xps = &smem[XPS + g * 65];
    for (int tt = 0; tt < Tt; ++tt) {
      float xt = xps[tt];
      float a0 = bias_r, a1 = bias_z, a2 = bh2s;
#pragma unroll
      for (int h = 0; h < 8; ++h) {
        a0 = fmaf(hall[h], w0s[h], a0);
        a1 = fmaf(hall[h], w1s[h], a1);
        a2 = fmaf(hall[h], w2s[h], a2);
      }
      float r = rcp_(1.0f + exp2_(fmaf(xt, wi0s, a0)));
      float z = rcp_(1.0f + exp2_(fmaf(xt, wi1s, a1)));
      float narg = fmaf(r, a2, fmaf(xt, wi2s, bi2s));
      float n = fmaf(-2.0f, rcp_(exp2_(narg) + 1.0f), 1.0f);
      float hn = fmaf(z, h_own - n, n);
      hdst[tt] = hn;
      h_own = hn;
#pragma unroll
      for (int h = 0; h < 8; ++h) hall[h] = __shfl(hn, base + h, 64);
    }
    __builtin_amdgcn_s_setprio(0);
  }
  __syncthreads();

  {
    float4* og = (float4*)(outp + (size_t)(b * Ff + f0) * Tt * Hh);
#pragma unroll
    for (int i = 0; i < 2; ++i) {
      int v = i * 256 + tid;
      int fl = v >> 7, rem = v & 127;
      int tt = rem >> 1, j0 = (rem & 1) * 4;
      const float* hp = &smem[HOUT + fl * 520 + j0 * 65 + tt];
      og[v] = make_float4(hp[0], hp[65], hp[130], hp[195]);
    }
  }

  {
    constexpr float SCL = 0.70710678118654752f * L2E;
    const float* hsrc = &smem[HOUT + w * 520];
    float* oc = &smem[OCT + w * 640];
    float* kk0 = &smem[KV + w * 1088];
    float* kk1 = kk0 + 272;
    float* vv0 = kk0 + 544;
    float* vv1 = kk0 + 816;

    float sq[8];
#pragma unroll
    for (int h = 0; h < 8; ++h) sq[h] = hsrc[h * 65 + t];
    float qv[8], ka[8], va[8];
#pragma unroll
    for (int jj = 0; jj < 8; ++jj) {
      float aq = in_b[jj], ak = in_b[8 + jj], av = in_b[16 + jj];
#pragma unroll
      for (int h = 0; h < 8; ++h) {
        aq = fmaf(sq[h], in_w[jj * 8 + h], aq);
        ak = fmaf(sq[h], in_w[(8 + jj) * 8 + h], ak);
        av = fmaf(sq[h], in_w[(16 + jj) * 8 + h], av);
      }
      qv[jj] = aq * SCL; ka[jj] = ak; va[jj] = av;
    }
#pragma unroll
    for (int n = 0; n < 4; ++n) {
      *(float2*)&oc[t * 10 + 2 * n] = make_float2(qv[2 * n], qv[2 * n + 1]);
      kk0[n * 68 + t] = ka[2 * n];
      kk1[n * 68 + t] = ka[2 * n + 1];
      vv0[n * 68 + t] = va[2 * n];
      vv1[n * 68 + t] = va[2 * n + 1];
    }
    asm volatile("s_waitcnt lgkmcnt(0)" ::: "memory");

    const int n = t >> 4, qq = t & 15;
    float q0[4], q1[4];
#pragma unroll
    for (int i = 0; i < 4; ++i) {
      float2 qp = *(const float2*)&oc[(qq + 16 * i) * 10 + 2 * n];
      q0[i] = qp.x; q1[i] = qp.y;
    }
    float ps[4], c0[4], c1[4];
#pragma unroll
    for (int i = 0; i < 4; ++i) { ps[i] = 0.f; c0[i] = 0.f; c1[i] = 0.f; }
#pragma unroll 2
    for (int kt4 = 0; kt4 < Tt; kt4 += 4) {
      float4 k0 = *(const float4*)&kk0[n * 68 + kt4];
      float4 k1 = *(const float4*)&kk1[n * 68 + kt4];
      float4 v0 = *(const float4*)&vv0[n * 68 + kt4];
      float4 v1 = *(const float4*)&vv1[n * 68 + kt4];
      MHA_STEP(k0.x, k1.x, v0.x, v1.x)
      MHA_STEP(k0.y, k1.y, v0.y, v1.y)
      MHA_STEP(k0.z, k1.z, v0.z, v1.z)
      MHA_STEP(k0.w, k1.w, v0.w, v1.w)
    }
#pragma unroll
    for (int i = 0; i < 4; ++i) {
      float inv = rcp_(ps[i]);
      *(float2*)&oc[(qq + 16 * i) * 10 + 2 * n] =
          make_float2(c0[i] * inv, c1[i] * inv);
    }
    asm volatile("s_waitcnt lgkmcnt(0)" ::: "memory");

    {
      float2 cp0 = *(const float2*)&oc[t * 10 + 0];
      float2 cp1 = *(const float2*)&oc[t * 10 + 2];
      float2 cp2 = *(const float2*)&oc[t * 10 + 4];
      float2 cp3 = *(const float2*)&oc[t * 10 + 6];
      float cx[8] = {cp0.x, cp0.y, cp1.x, cp1.y, cp2.x, cp2.y, cp3.x, cp3.y};
      float o8[8];
#pragma unroll
      for (int jj = 0; jj < 8; ++jj) {
        float a = ob[jj];
#pragma unroll
        for (int h = 0; h < 8; ++h) a = fmaf(cx[h], ow[jj * 8 + h], a);
        o8[jj] = a;
      }
      *(float2*)&oc[t * 10 + 0] = make_float2(o8[0], o8[1]);
      *(float2*)&oc[t * 10 + 2] = make_float2(o8[2], o8[3]);
      *(float2*)&oc[t * 10 + 4] = make_float2(o8[4], o8[5]);
      *(float2*)&oc[t * 10 + 6] = make_float2(o8[6], o8[7]);
    }
  }
  __syncthreads();

  {
#pragma unroll
    for (int i = 0; i < 2; ++i) {
      int v = i * 256 + tid;
      int tt = v >> 3, c = v & 7;
      int fl = c >> 1, h0 = (c & 1) * 4;
      const float* sp = &smem[OCT + fl * 640 + tt * 10 + h0];
      float4 val = make_float4(sp[0], sp[1], sp[2], sp[3]);
      *(float4*)(attn + (((size_t)b * Tt + tt) * Ff + f0 + fl) * Hh + h0) = val;
    }
  }
}

// ================= real K2: out_proj (R2 config) =================
__global__ __launch_bounds__(128) void k_outproj(
    const float* __restrict__ outp, const float* __restrict__ Wout,
    const float* __restrict__ bout, float* __restrict__ y) {
  constexpr int TT = 8;
  int blk = blockIdx.x;
  int b = blk >> 3;
  int t0 = (blk & 7) * TT;
  int tid = threadIdx.x;
  int oq = tid >> 4;
  int fc = tid & 15;
  float acc[TT][4];
#pragma unroll
  for (int tt = 0; tt < TT; ++tt)
#pragma unroll
    for (int od = 0; od < 4; ++od) acc[tt][od] = 0.f;
#pragma unroll
  for (int ff = 0; ff < 8; ++ff) {
    int f = fc * 8 + ff;
    const float4* rb = (const float4*)(outp + ((b * Ff + f) * Tt + t0) * Hh);
    float4 rv[16];
#pragma unroll
    for (int i = 0; i < 16; ++i) rv[i] = rb[i];
#pragma unroll
    for (int od = 0; od < 4; ++od) {
      int o = oq * 4 + od;
      const float4* wbp = (const float4*)(Wout + o * (Ff * Hh) + f * Hh);
      float4 wa = wbp[0], wc = wbp[1];
#pragma unroll
      for (int tt = 0; tt < TT; ++tt) {
        float4 ra = rv[tt * 2], rc = rv[tt * 2 + 1];
        float s = acc[tt][od];
        s = fmaf(ra.x, wa.x, s); s = fmaf(ra.y, wa.y, s);
        s = fmaf(ra.z, wa.z, s); s = fmaf(ra.w, wa.w, s);
        s = fmaf(rc.x, wc.x, s); s = fmaf(rc.y, wc.y, s);
        s = fmaf(rc.z, wc.z, s); s = fmaf(rc.w, wc.w, s);
        acc[tt][od] = s;
      }
    }
  }
#pragma unroll
  for (int tt = 0; tt < TT; ++tt)
#pragma unroll
    for (int od = 0; od < 4; ++od) {
      float v = acc[tt][od];
      v += __shfl_xor(v, 1, 16);
      v += __shfl_xor(v, 2, 16);
      v += __shfl_xor(v, 4, 16);
      v += __shfl_xor(v, 8, 16);
      acc[tt][od] = v;
    }
#pragma unroll
  for (int tt = 0; tt < TT; ++tt) {
    if (fc == tt) {
#pragma unroll
      for (int od = 0; od < 4; ++od) {
        int o = oq * 4 + od;
        y[(b * Tt + t0 + tt) * HIDh + o] = acc[tt][od] + bout[o];
      }
    }
  }
}

// ================= PROBE kp_A: phase A only -> scratch =================
__global__ __launch_bounds__(256) void kp_A(
    const float* __restrict__ x, const float* __restrict__ Wp,
    const float* __restrict__ bp, float* __restrict__ xq) {
  const int tid = threadIdx.x;
  const int t = tid & 63;
  const int w = tid >> 6;
  const int b = blockIdx.x >> 5;
  const int f0 = (blockIdx.x & 31) * 4;
  const int f = f0 + w;
  const float4* xr = (const float4*)(x + (b * Tt + t) * Ff);
  const float4* wr = (const float4*)(Wp + f * Ff);
  float acc = bp[f];
#pragma unroll 8
  for (int k = 0; k < Ff / 4; ++k) {
    float4 xv = xr[k], wv = wr[k];
    acc = fmaf(xv.x, wv.x, acc); acc = fmaf(xv.y, wv.y, acc);
    acc = fmaf(xv.z, wv.z, acc); acc = fmaf(xv.w, wv.w, acc);
  }
  xq[blockIdx.x * 256 + tid] = acc;   // coalesced scratch
}

// ================= PROBE kp_AB: phases A+B -> outp (identical values) =================
__global__ __launch_bounds__(256, 4) void kp_AB(
    const float* __restrict__ x, const float* __restrict__ Wp, const float* __restrict__ bp,
    const float* __restrict__ W_ih, const float* __restrict__ b_ih,
    const float* __restrict__ W_hh, const float* __restrict__ b_hh,
    float* __restrict__ outp) {
  __shared__ float smem[HOUT + 4 * 520];
  const int tid = threadIdx.x;
  const int t = tid & 63;
  const int w = tid >> 6;
  const int b = blockIdx.x >> 5;
  const int f0 = (blockIdx.x & 31) * 4;
  {
    const int f = f0 + w;
    const float4* xr = (const float4*)(x + (b * Tt + t) * Ff);
    const float4* wr = (const float4*)(Wp + f * Ff);
    float acc = bp[f];
#pragma unroll 8
    for (int k = 0; k < Ff / 4; ++k) {
      float4 xv = xr[k], wv = wr[k];
      acc = fmaf(xv.x, wv.x, acc); acc = fmaf(xv.y, wv.y, acc);
      acc = fmaf(xv.z, wv.z, acc); acc = fmaf(xv.w, wv.w, acc);
    }
    smem[XPS + w * 65 + t] = acc;
  }
  __syncthreads();
  if (tid < 32) {
    const int g = t >> 3, j = t & 7;
    const int f = f0 + g;
    const float* wb = W_hh + (f * G3H + j) * Hh;
    const float nL = -L2E, S2 = 2.0f * L2E;
    float w0s[8], w1s[8], w2s[8];
#pragma unroll
    for (int h = 0; h < 8; ++h) {
      w0s[h] = wb[h] * nL;
      w1s[h] = wb[64 + h] * nL;
      w2s[h] = wb[128 + h] * S2;
    }
    const float wi0s = W_ih[f * G3H + j] * nL;
    const float wi1s = W_ih[f * G3H + 8 + j] * nL;
    const float wi2s = W_ih[f * G3H + 16 + j] * S2;
    const float bias_r = (b_ih[f * G3H + j] + b_hh[f * G3H + j]) * nL;
    const float bias_z = (b_ih[f * G3H + 8 + j] + b_hh[f * G3H + 8 + j]) * nL;
    const float bi2s = b_ih[f * G3H + 16 + j] * S2;
    const float bh2s = b_hh[f * G3H + 16 + j] * S2;
    float hall[8];
#pragma unroll
    for (int h = 0; h < 8; ++h) hall[h] = 0.f;
    float h_own = 0.f;
    const int base = t & 56;
    float* hdst = &smem[HOUT + g * 520 + j * 65];
    const float* xps = &smem[XPS + g * 65];
    for (int tt = 0; tt < Tt; ++tt) {
      float xt = xps[tt];
      float a0 = bias_r, a1 = bias_z, a2 = bh2s;
#pragma unroll
      for (int h = 0; h < 8; ++h) {
        a0 = fmaf(hall[h], w0s[h], a0);
        a1 = fmaf(hall[h], w1s[h], a1);
        a2 = fmaf(hall[h], w2s[h], a2);
      }
      float r = rcp_(1.0f + exp2_(fmaf(xt, wi0s, a0)));
      float z = rcp_(1.0f + exp2_(fmaf(xt, wi1s, a1)));
      float narg = fmaf(r, a2, fmaf(xt, wi2s, bi2s));
      float n = fmaf(-2.0f, rcp_(exp2_(narg) + 1.0f), 1.0f);
      float hn = fmaf(z, h_own - n, n);
      hdst[tt] = hn;
      h_own = hn;
#pragma unroll
      for (int h = 0; h < 8; ++h) hall[h] = __shfl(hn, base + h, 64);
    }
  }
  __syncthreads();
  {
    float4* og = (float4*)(outp + (size_t)(b * Ff + f0) * Tt * Hh);
#pragma unroll
    for (int i = 0; i < 2; ++i) {
      int v = i * 256 + tid;
      int fl = v >> 7, rem = v & 127;
      int tt = rem >> 1, j0 = (rem & 1) * 4;
      const float* hp = &smem[HOUT + fl * 520 + j0 * 65 + tt];
      og[v] = make_float4(hp[0], hp[65], hp[130], hp[195]);
    }
  }
}

// ================= PROBE kp_C<STORE>: MHA from outp; store attn or asm-sink =================
template <int STORE>
__global__ __launch_bounds__(256) void kp_C(
    const float* __restrict__ outp, const float* __restrict__ in_w,
    const float* __restrict__ in_b, const float* __restrict__ ow,
    const float* __restrict__ ob, float* __restrict__ attn) {
  __shared__ float smem[SM_C];
  const int tid = threadIdx.x;
  const int t = tid & 63;
  const int w = tid >> 6;
  const int b = blockIdx.x >> 5;
  const int f0 = (blockIdx.x & 31) * 4;
  constexpr float SCL = 0.70710678118654752f * L2E;
  float* oc = &smem[OCT2 + w * 640];
  float* kk0 = &smem[KV2 + w * 1088];
  float* kk1 = kk0 + 272;
  float* vv0 = kk0 + 544;
  float* vv1 = kk0 + 816;

  // h row t from global (coalesced within wave)
  const float4* src = (const float4*)(outp + (size_t)(b * Ff + f0 + w) * Tt * Hh);
  float4 r0 = src[t * 2], r1 = src[t * 2 + 1];
  float sq[8] = {r0.x, r0.y, r0.z, r0.w, r1.x, r1.y, r1.z, r1.w};
  float qv[8], ka[8], va[8];
#pragma unroll
  for (int jj = 0; jj < 8; ++jj) {
    float aq = in_b[jj], ak = in_b[8 + jj], av = in_b[16 + jj];
#pragma unroll
    for (int h = 0; h < 8; ++h) {
      aq = fmaf(sq[h], in_w[jj * 8 + h], aq);
      ak = fmaf(sq[h], in_w[(8 + jj) * 8 + h], ak);
      av = fmaf(sq[h], in_w[(16 + jj) * 8 + h], av);
    }
    qv[jj] = aq * SCL; ka[jj] = ak; va[jj] = av;
  }
#pragma unroll
  for (int n = 0; n < 4; ++n) {
    *(float2*)&oc[t * 10 + 2 * n] = make_float2(qv[2 * n], qv[2 * n + 1]);
    kk0[n * 68 + t] = ka[2 * n];
    kk1[n * 68 + t] = ka[2 * n + 1];
    vv0[n * 68 + t] = va[2 * n];
    vv1[n * 68 + t] = va[2 * n + 1];
  }
  asm volatile("s_waitcnt lgkmcnt(0)" ::: "memory");

  const int n = t >> 4, qq = t & 15;
  float q0[4], q1[4];
#pragma unroll
  for (int i = 0; i < 4; ++i) {
    float2 qp = *(const float2*)&oc[(qq + 16 * i) * 10 + 2 * n];
    q0[i] = qp.x; q1[i] = qp.y;
  }
  float ps[4], c0[4], c1[4];
#pragma unroll
  for (int i = 0; i < 4; ++i) { ps[i] = 0.f; c0[i] = 0.f; c1[i] = 0.f; }
#pragma unroll 2
  for (int kt4 = 0; kt4 < Tt; kt4 += 4) {
    float4 k0 = *(const float4*)&kk0[n * 68 + kt4];
    float4 k1 = *(const float4*)&kk1[n * 68 + kt4];
    float4 v0 = *(const float4*)&vv0[n * 68 + kt4];
    float4 v1 = *(const float4*)&vv1[n * 68 + kt4];
    MHA_STEP(k0.x, k1.x, v0.x, v1.x)
    MHA_STEP(k0.y, k1.y, v0.y, v1.y)
    MHA_STEP(k0.z, k1.z, v0.z, v1.z)
    MHA_STEP(k0.w, k1.w, v0.w, v1.w)
  }
#pragma unroll
  for (int i = 0; i < 4; ++i) {
    float inv = rcp_(ps[i]);
    *(float2*)&oc[(qq + 16 * i) * 10 + 2 * n] =
        make_float2(c0[i] * inv, c1[i] * inv);
  }
  asm volatile("s_waitcnt lgkmcnt(0)" ::: "memory");

  float2 cp0 = *(const float2*)&oc[t * 10 + 0];
  float2 cp1 = *(const float2*)&oc[t * 10 + 2];
  float2 cp2 = *(const float2*)&oc[t * 10 + 4];
  float2 cp3 = *(const float2*)&oc[t * 10 + 6];
  float cx[8] = {cp0.x, cp0.y, cp1.x, cp1.y, cp2.x, cp2.y, cp3.x, cp3.y};
  float o8[8];
#pragma unroll
  for (int jj = 0; jj < 8; ++jj) {
    float a = ob[jj];
#pragma unroll
    for (int h = 0; h < 8; ++h) a = fmaf(cx[h], ow[jj * 8 + h], a);
    o8[jj] = a;
  }
  if (STORE) {
    *(float2*)&oc[t * 10 + 0] = make_float2(o8[0], o8[1]);
    *(float2*)&oc[t * 10 + 2] = make_float2(o8[2], o8[3]);
    *(float2*)&oc[t * 10 + 4] = make_float2(o8[4], o8[5]);
    *(float2*)&oc[t * 10 + 6] = make_float2(o8[6], o8[7]);
    __syncthreads();
#pragma unroll
    for (int i = 0; i < 2; ++i) {
      int v = i * 256 + tid;
      int tt = v >> 3, c = v & 7;
      int fl = c >> 1, h0 = (c & 1) * 4;
      const float* sp = &smem[OCT2 + fl * 640 + tt * 10 + h0];
      float4 val = make_float4(sp[0], sp[1], sp[2], sp[3]);
      *(float4*)(attn + (((size_t)b * Tt + tt) * Ff + f0 + fl) * Hh + h0) = val;
    }
  } else {
    // keep full chain live without any store (rule #17)
#pragma unroll
    for (int jj = 0; jj < 8; ++jj) asm volatile("" ::"v"(o8[jj]));
  }
}

extern "C" void kernel_launch(void* const* d_in, const int* in_sizes, int n_in,
                              void* d_out, int out_size, void* d_ws, size_t ws_size,
                              hipStream_t stream) {
  (void)in_sizes; (void)n_in; (void)out_size; (void)ws_size;
  const float* x    = (const float*)d_in[0];
  const float* Wp   = (const float*)d_in[1];
  const float* bp   = (const float*)d_in[2];
  const float* W_ih = (const float*)d_in[3];
  const float* b_ih = (const float*)d_in[4];
  const float* W_hh = (const float*)d_in[5];
  const float* b_hh = (const float*)d_in[6];
  const float* in_w = (const float*)d_in[7];
  const float* in_b = (const float*)d_in[8];
  const float* ow   = (const float*)d_in[9];
  const float* ob   = (const float*)d_in[10];
  const float* Wout = (const float*)d_in[11];
  const float* bout = (const float*)d_in[12];

  float* y    = (float*)d_out;
  float* attn = (float*)d_out + Bb * Tt * HIDh;
  float* outp = (float*)d_ws;                          // B*F*T*H = 2M floats
  float* xq   = (float*)d_ws + Bb * Ff * Tt * Hh;      // probe scratch (256K floats)

  // real pipeline
  hipLaunchKernelGGL(k_fused, dim3(Bb * (Ff / 4)), dim3(256), 0, stream,
                     x, Wp, bp, W_ih, b_ih, W_hh, b_hh, in_w, in_b, ow, ob, outp, attn);
  hipLaunchKernelGGL(k_outproj, dim3(Bb * (Tt / 8)), dim3(128), 0, stream,
                     outp, Wout, bout, y);
  // probes (output-safe; see header comment)
  hipLaunchKernelGGL(kp_A, dim3(Bb * (Ff / 4)), dim3(256), 0, stream, x, Wp, bp, xq);
  hipLaunchKernelGGL(HIP_KERNEL_NAME(kp_C<0>), dim3(Bb * (Ff / 4)), dim3(256), 0, stream,
                     outp, in_w, in_b, ow, ob, attn);
  hipLaunchKernelGGL(HIP_KERNEL_NAME(kp_C<1>), dim3(Bb * (Ff / 4)), dim3(256), 0, stream,
                     outp, in_w, in_b, ow, ob, attn);
  hipLaunchKernelGGL(kp_AB, dim3(Bb * (Ff / 4)), dim3(256), 0, stream,
                     x, Wp, bp, W_ih, b_ih, W_hh, b_hh, outp);
}

// Round 13
// 131.003 us; speedup vs baseline: 1.0887x; 1.0887x over previous
//
#include <hip/hip_runtime.h>

// MHAGRU, single compute kernel + y-zeroing memset.
// k_fused: inproj + GRU + y-partials(atomicAdd) + MHA, one block per (b, 4f).
// B=32 T=64 F=128 H=8 NH=4 HD=2 HID=32. All f32.
// d_out = [ y (B*T*HID) | attention (B*T*F*H) ]; d_ws unused.
//
// R13: out_proj folded into k_fused as per-block partials + global atomicAdd
// (2M f32 atomics, issued BEFORE phase C so they drain under C2 compute).
// y zeroed each call via hipMemsetAsync (harness-sanctioned self-init);
// bout contributed once by the f0==0 blocks. outp (8MB ws write + re-read)
// and the second launch are gone. R11 phase bodies otherwise verbatim.

namespace {
constexpr int Bb = 32, Tt = 64, Ff = 128, Hh = 8, HIDh = 32;
constexpr int G3H = 24;
constexpr float L2E = 1.44269504088896340736f;
// LDS (floats), all regions disjoint:
constexpr int XPS  = 0;                    // xp [4 f][65 t]
constexpr int HOUT = 260;                  // h  [4 f][8 j][65 t]
constexpr int OCT  = 2340;                 // q/ctx/o8 [4 f][64 t][10]
constexpr int KV   = 4900;                 // per wave: kk0|kk1|vv0|vv1 [4][68]
constexpr int SM_SIZE = KV + 4 * 1088;     // 9252 floats = 37.0 KB
}

__device__ __forceinline__ float rcp_(float x) {
#if __has_builtin(__builtin_amdgcn_rcpf)
  return __builtin_amdgcn_rcpf(x);
#else
  return 1.0f / x;
#endif
}
__device__ __forceinline__ float exp2_(float x) {
#if __has_builtin(__builtin_amdgcn_exp2f)
  return __builtin_amdgcn_exp2f(x);
#else
  return exp2f(x);
#endif
}

#define MHA_STEP(K0C, K1C, V0C, V1C)                         \
  {                                                          \
    _Pragma("unroll") for (int i = 0; i < 4; ++i) {          \
      float s = fmaf(q0[i], K0C, q1[i] * K1C);               \
      float p = exp2_(s);                                    \
      ps[i] += p;                                            \
      c0[i] = fmaf(p, V0C, c0[i]);                           \
      c1[i] = fmaf(p, V1C, c1[i]);                           \
    }                                                        \
  }

// ---------------- K1: one block per (b, 4f); 256 threads = 4 waves ----------------
__global__ __launch_bounds__(256, 4) void k_fused(
    const float* __restrict__ x, const float* __restrict__ Wp, const float* __restrict__ bp,
    const float* __restrict__ W_ih, const float* __restrict__ b_ih,
    const float* __restrict__ W_hh, const float* __restrict__ b_hh,
    const float* __restrict__ in_w, const float* __restrict__ in_b,
    const float* __restrict__ ow, const float* __restrict__ ob,
    const float* __restrict__ Wout, const float* __restrict__ bout,
    float* __restrict__ y, float* __restrict__ attn) {
  __shared__ float smem[SM_SIZE];
  const int tid = threadIdx.x;
  const int t = tid & 63;
  const int w = tid >> 6;
  const int blk = blockIdx.x;
  const int b = blk >> 5;
  const int f0 = (blk & 31) * 4;

  // ---- phase A: wave w computes xp[:, f0+w]; x rows from global (L1/L2) ----
  {
    const int f = f0 + w;
    const float4* xr = (const float4*)(x + (b * Tt + t) * Ff);
    const float4* wr = (const float4*)(Wp + f * Ff);   // wave-uniform -> scalar
    float acc = bp[f];
#pragma unroll 8
    for (int k = 0; k < Ff / 4; ++k) {
      float4 xv = xr[k], wv = wr[k];
      acc = fmaf(xv.x, wv.x, acc); acc = fmaf(xv.y, wv.y, acc);
      acc = fmaf(xv.z, wv.z, acc); acc = fmaf(xv.w, wv.w, acc);
    }
    smem[XPS + w * 65 + t] = acc;
  }
  __syncthreads();

  // ---- phase B: GRU scan, wave 0 lanes 0..31 (g=f_local, j=hidden) ----
  if (tid < 32) {
    __builtin_amdgcn_s_setprio(1);
    const int g = t >> 3, j = t & 7;
    const int f = f0 + g;
    const float* wb = W_hh + (f * G3H + j) * Hh;
    const float nL = -L2E, S2 = 2.0f * L2E;
    float w0s[8], w1s[8], w2s[8];
#pragma unroll
    for (int h = 0; h < 8; ++h) {
      w0s[h] = wb[h] * nL;
      w1s[h] = wb[64 + h] * nL;
      w2s[h] = wb[128 + h] * S2;
    }
    const float wi0s = W_ih[f * G3H + j] * nL;
    const float wi1s = W_ih[f * G3H + 8 + j] * nL;
    const float wi2s = W_ih[f * G3H + 16 + j] * S2;
    const float bias_r = (b_ih[f * G3H + j] + b_hh[f * G3H + j]) * nL;
    const float bias_z = (b_ih[f * G3H + 8 + j] + b_hh[f * G3H + 8 + j]) * nL;
    const float bi2s = b_ih[f * G3H + 16 + j] * S2;
    const float bh2s = b_hh[f * G3H + 16 + j] * S2;
    float hall[8];
#pragma unroll
    for (int h = 0; h < 8; ++h) hall[h] = 0.f;
    float h_own = 0.f;                   // == hall[j] without dynamic index
    const int base = t & 56;
    float* hdst = &smem[HOUT + g * 520 + j * 65];
    const float* xps = &smem[XPS + g * 65];
    for (int tt = 0; tt < Tt; ++tt) {
      float xt = xps[tt];
      float a0 = bias_r, a1 = bias_z, a2 = bh2s;
#pragma unroll
      for (int h = 0; h < 8; ++h) {
        a0 = fmaf(hall[h], w0s[h], a0);
        a1 = fmaf(hall[h], w1s[h], a1);
        a2 = fmaf(hall[h], w2s[h], a2);
      }
      float r = rcp_(1.0f + exp2_(fmaf(xt, wi0s, a0)));
      float z = rcp_(1.0f + exp2_(fmaf(xt, wi1s, a1)));
      float narg = fmaf(r, a2, fmaf(xt, wi2s, bi2s));
      float n = fmaf(-2.0f, rcp_(exp2_(narg) + 1.0f), 1.0f);  // tanh
      float hn = fmaf(z, h_own - n, n);
      hdst[tt] = hn;
      h_own = hn;
#pragma unroll
      for (int h = 0; h < 8; ++h) hall[h] = __shfl(hn, base + h, 64);
    }
    __builtin_amdgcn_s_setprio(0);
  }
  __syncthreads();   // hout ready for all waves

  // ---- phase D: y partials + atomicAdd (fire early; drains under phase C) ----
  // wave w owns o in [8w, 8w+8); lane t: part[o] = sum_{fl,h} h[fl][h][t]*Wout[o][(f0+fl)*8+h]
  {
    const int od0 = w * 8;
    float part[8];
#pragma unroll
    for (int od = 0; od < 8; ++od) part[od] = 0.f;
#pragma unroll
    for (int fl = 0; fl < 4; ++fl) {
      float hv[8];
#pragma unroll
      for (int h = 0; h < 8; ++h) hv[h] = smem[HOUT + fl * 520 + h * 65 + t];
#pragma unroll
      for (int od = 0; od < 8; ++od) {
        const float4* wq = (const float4*)(Wout + (od0 + od) * (Ff * Hh) + (f0 + fl) * Hh);
        float4 wa = wq[0], wb4 = wq[1];   // wave-uniform -> scalar loads
        float s = part[od];
        s = fmaf(hv[0], wa.x, s);  s = fmaf(hv[1], wa.y, s);
        s = fmaf(hv[2], wa.z, s);  s = fmaf(hv[3], wa.w, s);
        s = fmaf(hv[4], wb4.x, s); s = fmaf(hv[5], wb4.y, s);
        s = fmaf(hv[6], wb4.z, s); s = fmaf(hv[7], wb4.w, s);
        part[od] = s;
      }
    }
    if ((blk & 31) == 0) {            // bout contributed exactly once per (b)
#pragma unroll
      for (int od = 0; od < 8; ++od) part[od] += bout[od0 + od];
    }
    float* yb = y + ((size_t)b * Tt + t) * HIDh + od0;
#pragma unroll
    for (int od = 0; od < 8; ++od) atomicAdd(&yb[od], part[od]);
  }

  // ---- phase C: wave w handles f = f0 + w (one feature, wave-private) ----
  {
    constexpr float SCL = 0.70710678118654752f * L2E;
    const float* hsrc = &smem[HOUT + w * 520];
    float* oc = &smem[OCT + w * 640];
    float* kk0 = &smem[KV + w * 1088];
    float* kk1 = kk0 + 272;
    float* vv0 = kk0 + 544;
    float* vv1 = kk0 + 816;

    // C1: lane t = time row; qkv projection from LDS-resident h
    float sq[8];
#pragma unroll
    for (int h = 0; h < 8; ++h) sq[h] = hsrc[h * 65 + t];   // conflict-free
    float qv[8], ka[8], va[8];
#pragma unroll
    for (int jj = 0; jj < 8; ++jj) {
      float aq = in_b[jj], ak = in_b[8 + jj], av = in_b[16 + jj];
#pragma unroll
      for (int h = 0; h < 8; ++h) {
        aq = fmaf(sq[h], in_w[jj * 8 + h], aq);
        ak = fmaf(sq[h], in_w[(8 + jj) * 8 + h], ak);
        av = fmaf(sq[h], in_w[(16 + jj) * 8 + h], av);
      }
      qv[jj] = aq * SCL; ka[jj] = ak; va[jj] = av;
    }
#pragma unroll
    for (int n = 0; n < 4; ++n) {
      *(float2*)&oc[t * 10 + 2 * n] = make_float2(qv[2 * n], qv[2 * n + 1]);
      kk0[n * 68 + t] = ka[2 * n];
      kk1[n * 68 + t] = ka[2 * n + 1];
      vv0[n * 68 + t] = va[2 * n];
      vv1[n * 68 + t] = va[2 * n + 1];
    }
    asm volatile("s_waitcnt lgkmcnt(0)" ::: "memory");   // within-wave RAW

    // C2: lane = (n = t>>4, qq = t&15); 4 q-rows x 1 head; kv b128 broadcast
    const int n = t >> 4, qq = t & 15;
    float q0[4], q1[4];
#pragma unroll
    for (int i = 0; i < 4; ++i) {
      float2 qp = *(const float2*)&oc[(qq + 16 * i) * 10 + 2 * n];
      q0[i] = qp.x; q1[i] = qp.y;
    }
    float ps[4], c0[4], c1[4];
#pragma unroll
    for (int i = 0; i < 4; ++i) { ps[i] = 0.f; c0[i] = 0.f; c1[i] = 0.f; }
#pragma unroll 2
    for (int kt4 = 0; kt4 < Tt; kt4 += 4) {
      float4 k0 = *(const float4*)&kk0[n * 68 + kt4];
      float4 k1 = *(const float4*)&kk1[n * 68 + kt4];
      float4 v0 = *(const float4*)&vv0[n * 68 + kt4];
      float4 v1 = *(const float4*)&vv1[n * 68 + kt4];
      MHA_STEP(k0.x, k1.x, v0.x, v1.x)
      MHA_STEP(k0.y, k1.y, v0.y, v1.y)
      MHA_STEP(k0.z, k1.z, v0.z, v1.z)
      MHA_STEP(k0.w, k1.w, v0.w, v1.w)
    }
#pragma unroll
    for (int i = 0; i < 4; ++i) {
      float inv = rcp_(ps[i]);
      *(float2*)&oc[(qq + 16 * i) * 10 + 2 * n] =
          make_float2(c0[i] * inv, c1[i] * inv);   // ctx overwrites q
    }
    asm volatile("s_waitcnt lgkmcnt(0)" ::: "memory");

    // C3: lane t: out_proj(ow,ob) of ctx row t, o8 back into own row
    {
      float2 cp0 = *(const float2*)&oc[t * 10 + 0];
      float2 cp1 = *(const float2*)&oc[t * 10 + 2];
      float2 cp2 = *(const float2*)&oc[t * 10 + 4];
      float2 cp3 = *(const float2*)&oc[t * 10 + 6];
      float cx[8] = {cp0.x, cp0.y, cp1.x, cp1.y, cp2.x, cp2.y, cp3.x, cp3.y};
      float o8[8];
#pragma unroll
      for (int jj = 0; jj < 8; ++jj) {
        float a = ob[jj];
#pragma unroll
        for (int h = 0; h < 8; ++h) a = fmaf(cx[h], ow[jj * 8 + h], a);
        o8[jj] = a;
      }
      *(float2*)&oc[t * 10 + 0] = make_float2(o8[0], o8[1]);
      *(float2*)&oc[t * 10 + 2] = make_float2(o8[2], o8[3]);
      *(float2*)&oc[t * 10 + 4] = make_float2(o8[4], o8[5]);
      *(float2*)&oc[t * 10 + 6] = make_float2(o8[6], o8[7]);
    }
  }
  __syncthreads();

  // ---- attn burst store: per t, 4f x 8h = 128B contiguous (full L2 lines) ----
  {
#pragma unroll
    for (int i = 0; i < 2; ++i) {
      int v = i * 256 + tid;              // float4 index (512 total)
      int tt = v >> 3, c = v & 7;
      int fl = c >> 1, h0 = (c & 1) * 4;
      const float* sp = &smem[OCT + fl * 640 + tt * 10 + h0];
      float4 val = make_float4(sp[0], sp[1], sp[2], sp[3]);
      *(float4*)(attn + (((size_t)b * Tt + tt) * Ff + f0 + fl) * Hh + h0) = val;
    }
  }
}

extern "C" void kernel_launch(void* const* d_in, const int* in_sizes, int n_in,
                              void* d_out, int out_size, void* d_ws, size_t ws_size,
                              hipStream_t stream) {
  (void)in_sizes; (void)n_in; (void)out_size; (void)d_ws; (void)ws_size;
  const float* x    = (const float*)d_in[0];
  const float* Wp   = (const float*)d_in[1];
  const float* bp   = (const float*)d_in[2];
  const float* W_ih = (const float*)d_in[3];
  const float* b_ih = (const float*)d_in[4];
  const float* W_hh = (const float*)d_in[5];
  const float* b_hh = (const float*)d_in[6];
  const float* in_w = (const float*)d_in[7];
  const float* in_b = (const float*)d_in[8];
  const float* ow   = (const float*)d_in[9];
  const float* ob   = (const float*)d_in[10];
  const float* Wout = (const float*)d_in[11];
  const float* bout = (const float*)d_in[12];

  float* y    = (float*)d_out;                   // B*T*HID (atomic-accumulated)
  float* attn = (float*)d_out + Bb * Tt * HIDh;  // B*T*F*H

  // zero y each call (harness poisons d_out once; we own re-init). Graph-safe.
  hipMemsetAsync(y, 0, (size_t)Bb * Tt * HIDh * sizeof(float), stream);

  hipLaunchKernelGGL(k_fused, dim3(Bb * (Ff / 4)), dim3(256), 0, stream,
                     x, Wp, bp, W_ih, b_ih, W_hh, b_hh, in_w, in_b, ow, ob,
                     Wout, bout, y, attn);
}

// Round 14
// 52.734 us; speedup vs baseline: 2.7046x; 2.4842x over previous
//
#include <hip/hip_runtime.h>

// MHAGRU, 2 kernels: [inproj + GRU + MHA fused, h LDS-resident] -> [out_proj].
// B=32 T=64 F=128 H=8 NH=4 HD=2 HID=32. f32 compute; bf16 ws intermediate.
// d_out = [ y (B*T*HID) | attention (B*T*F*H) ]
// d_ws  = [ out_bf16 (B*F,T,H) ushort ] (written by K1, read only by K2)
//
// R14: R9 (best known, 56.9us) + bf16 outp intermediate (halves K1's ws write
// and K2's read; y-path precision cost ~3e-3 << 3.4e-2 threshold; attn path
// unchanged -- MHA consumes f32 h from LDS). R13's atomics reverted (9x write
// amplification). All R9-proven phase bodies byte-identical otherwise.

namespace {
constexpr int Bb = 32, Tt = 64, Ff = 128, Hh = 8, HIDh = 32;
constexpr int G3H = 24;
constexpr float L2E = 1.44269504088896340736f;
// K1 LDS (floats), phased overlays (R9):
//  phase A: xs [0,8320) stride 130; xp [8320,8840)
//  phase B: hout [0,4160) (overlays xs); xp read
//  phase C: hout; OCT [4160,9280); WKV [9280,16192) 1728/wave
constexpr int XS_STRIDE = 130;
constexpr int XP = 8320;
constexpr int OCT = 4160;                 // o8 staging [8 f][64 t][10]
constexpr int WKV = 9280;                 // per-wave kv/q region
constexpr int KK0 = 0, KK1 = 272, VV0 = 544, VV1 = 816, QS = 1088;  // within WKV
constexpr int SM_SIZE = 16192;            // 64.8 KB -> 2 blocks/CU
}

__device__ __forceinline__ float rcp_(float x) {
#if __has_builtin(__builtin_amdgcn_rcpf)
  return __builtin_amdgcn_rcpf(x);
#else
  return 1.0f / x;
#endif
}
__device__ __forceinline__ float exp2_(float x) {
#if __has_builtin(__builtin_amdgcn_exp2f)
  return __builtin_amdgcn_exp2f(x);
#else
  return exp2f(x);
#endif
}
// f32 -> bf16 (round-to-nearest-even), packed pair -> one dword
__device__ __forceinline__ unsigned bfp_(float a, float b) {
  union { float f; unsigned u; } ca{a}, cb{b};
  unsigned ra = (ca.u + 0x7fffu + ((ca.u >> 16) & 1u)) >> 16;
  unsigned rb = (cb.u + 0x7fffu + ((cb.u >> 16) & 1u)) >> 16;
  return ra | (rb << 16);
}
__device__ __forceinline__ float bflo_(unsigned u) { return __uint_as_float(u << 16); }
__device__ __forceinline__ float bfhi_(unsigned u) { return __uint_as_float(u & 0xffff0000u); }

// 4-row softmax+PV step per kv component (R6/R8/R9 proven)
#define MHA_STEP(K0C, K1C, V0C, V1C)                         \
  {                                                          \
    _Pragma("unroll") for (int i = 0; i < 4; ++i) {          \
      float s = fmaf(q0[i], K0C, q1[i] * K1C);               \
      float p = exp2_(s);                                    \
      ps[i] += p;                                            \
      c0[i] = fmaf(p, V0C, c0[i]);                           \
      c1[i] = fmaf(p, V1C, c1[i]);                           \
    }                                                        \
  }

// ---------------- K1: input_proj + GRU + MHA, one block per (b, 8f) ----------------
// grid: B*(F/8) = 512 blocks, 256 threads = 4 waves.
__global__ __launch_bounds__(256, 2) void k_fused(
    const float* __restrict__ x, const float* __restrict__ Wp, const float* __restrict__ bp,
    const float* __restrict__ W_ih, const float* __restrict__ b_ih,
    const float* __restrict__ W_hh, const float* __restrict__ b_hh,
    const float* __restrict__ in_w, const float* __restrict__ in_b,
    const float* __restrict__ ow, const float* __restrict__ ob,
    ushort* __restrict__ outp, float* __restrict__ attn) {
  __shared__ float smem[SM_SIZE];
  const int tid = threadIdx.x;
  const int blk = blockIdx.x;
  const int b = blk >> 4;
  const int f0 = (blk & 15) * 8;
  const int lane = tid & 63;
  const int w = tid >> 6;

  // ---- phase A: stage x[b] (64x128); compute xp for this block's 8 f's ----
  {
    const float2* xb = (const float2*)(x + b * Tt * Ff);
    for (int i = tid; i < Tt * Ff / 2; i += 256) {
      int row = i >> 6, col2 = i & 63;
      *(float2*)&smem[row * XS_STRIDE + col2 * 2] = xb[i];
    }
  }
  __syncthreads();
  {
    const int t = lane;
    const int fA = f0 + w, fB = f0 + w + 4;  // wave-uniform -> scalar Wp loads
    float acc0 = bp[fA], acc1 = bp[fB];
    const float* wA = Wp + fA * Ff;
    const float* wB = Wp + fB * Ff;
    const float* xr = &smem[t * XS_STRIDE];
#pragma unroll 8
    for (int k = 0; k < Ff; k += 2) {
      float2 xv = *(const float2*)&xr[k];
      acc0 = fmaf(xv.x, wA[k], acc0); acc0 = fmaf(xv.y, wA[k + 1], acc0);
      acc1 = fmaf(xv.x, wB[k], acc1); acc1 = fmaf(xv.y, wB[k + 1], acc1);
    }
    smem[XP + w * 65 + t] = acc0;
    smem[XP + (w + 4) * 65 + t] = acc1;
  }
  __syncthreads();   // xp ready; xs region dead -> hout overlays it

  // ---- phase B: GRU scan over T, wave 0 only; h -> LDS ----
  if (tid < 64) {
    __builtin_amdgcn_s_setprio(1);
    const int g = tid >> 3, j = tid & 7;
    const int f = f0 + g;
    const float* wb = W_hh + (f * G3H + j) * Hh;
    const float nL = -L2E, S2 = 2.0f * L2E;
    float w0s[8], w1s[8], w2s[8];
#pragma unroll
    for (int h = 0; h < 8; ++h) {
      w0s[h] = wb[h] * nL;
      w1s[h] = wb[64 + h] * nL;
      w2s[h] = wb[128 + h] * S2;
    }
    const float wi0s = W_ih[f * G3H + j] * nL;
    const float wi1s = W_ih[f * G3H + 8 + j] * nL;
    const float wi2s = W_ih[f * G3H + 16 + j] * S2;
    const float bias_r = (b_ih[f * G3H + j] + b_hh[f * G3H + j]) * nL;
    const float bias_z = (b_ih[f * G3H + 8 + j] + b_hh[f * G3H + 8 + j]) * nL;
    const float bi2s = b_ih[f * G3H + 16 + j] * S2;
    const float bh2s = b_hh[f * G3H + 16 + j] * S2;
    float hall[8];
#pragma unroll
    for (int h = 0; h < 8; ++h) hall[h] = 0.f;
    float h_own = 0.f;
    const int base = tid & 56;
    float* hdst = &smem[g * 520 + j * 65];   // hout[g][j][t]
    const float* xps = &smem[XP + g * 65];
    for (int t = 0; t < Tt; ++t) {
      float xt = xps[t];
      float a0 = bias_r, a1 = bias_z, a2 = bh2s;
#pragma unroll
      for (int h = 0; h < 8; ++h) {
        a0 = fmaf(hall[h], w0s[h], a0);
        a1 = fmaf(hall[h], w1s[h], a1);
        a2 = fmaf(hall[h], w2s[h], a2);
      }
      float r = rcp_(1.0f + exp2_(fmaf(xt, wi0s, a0)));
      float z = rcp_(1.0f + exp2_(fmaf(xt, wi1s, a1)));
      float narg = fmaf(r, a2, fmaf(xt, wi2s, bi2s));
      float n = fmaf(-2.0f, rcp_(exp2_(narg) + 1.0f), 1.0f);  // tanh
      float hn = fmaf(z, h_own - n, n);
      hdst[t] = hn;
      h_own = hn;
#pragma unroll
      for (int h = 0; h < 8; ++h) hall[h] = __shfl(hn, base + h, 64);
    }
    __builtin_amdgcn_s_setprio(0);
  }
  __syncthreads();   // hout ready for all waves

  // ---- burst-write h tile to global as bf16: 8f x 64t rows of 8 bf16 (16B each) ----
  {
    ushort* og = outp + (size_t)(b * Ff + f0) * Tt * Hh;
#pragma unroll
    for (int i = 0; i < 2; ++i) {
      int v = i * 256 + tid;               // row index (512 total)
      int fl = v >> 6, tt = v & 63;
      const float* hp = &smem[fl * 520 + tt];
      unsigned d0 = bfp_(hp[0],   hp[65]);
      unsigned d1 = bfp_(hp[130], hp[195]);
      unsigned d2 = bfp_(hp[260], hp[325]);
      unsigned d3 = bfp_(hp[390], hp[455]);
      *(uint4*)(og + (size_t)v * 8) = make_uint4(d0, d1, d2, d3);
    }
  }

  // ---- phase C: MHA; wave w handles f_local = w and w+4, fully wave-private ----
  {
    const int t = lane;
    float* sm = &smem[WKV + w * 1728];
    constexpr float SCL = 0.70710678118654752f * L2E;
#pragma unroll
    for (int fl = w; fl < 8; fl += 4) {
      const float* hsrc = &smem[fl * 520];
      // C1: qkv projection from LDS-resident f32 h
      float sq[8];
#pragma unroll
      for (int h = 0; h < 8; ++h) sq[h] = hsrc[h * 65 + t];
      float qv[8], ka[8], va[8];
#pragma unroll
      for (int jj = 0; jj < 8; ++jj) {
        float aq = in_b[jj], ak = in_b[8 + jj], av = in_b[16 + jj];
#pragma unroll
        for (int h = 0; h < 8; ++h) {
          aq = fmaf(sq[h], in_w[jj * 8 + h], aq);
          ak = fmaf(sq[h], in_w[(8 + jj) * 8 + h], ak);
          av = fmaf(sq[h], in_w[(16 + jj) * 8 + h], av);
        }
        qv[jj] = aq * SCL; ka[jj] = ak; va[jj] = av;
      }
#pragma unroll
      for (int n = 0; n < 4; ++n) {
        *(float2*)&sm[QS + t * 10 + 2 * n] = make_float2(qv[2 * n], qv[2 * n + 1]);
        sm[KK0 + n * 68 + t] = ka[2 * n];
        sm[KK1 + n * 68 + t] = ka[2 * n + 1];
        sm[VV0 + n * 68 + t] = va[2 * n];
        sm[VV1 + n * 68 + t] = va[2 * n + 1];
      }
      asm volatile("s_waitcnt lgkmcnt(0)" ::: "memory");  // within-wave RAW

      // C2: lane = (n = t>>4, qq = t&15); 4 q-rows x 1 head
      const int n = t >> 4, qq = t & 15;
      float q0[4], q1[4];
#pragma unroll
      for (int i = 0; i < 4; ++i) {
        float2 qp = *(const float2*)&sm[QS + (qq + 16 * i) * 10 + 2 * n];
        q0[i] = qp.x; q1[i] = qp.y;
      }
      float ps[4], c0[4], c1[4];
#pragma unroll
      for (int i = 0; i < 4; ++i) { ps[i] = 0.f; c0[i] = 0.f; c1[i] = 0.f; }
#pragma unroll 2
      for (int kt4 = 0; kt4 < Tt; kt4 += 4) {
        float4 k0 = *(const float4*)&sm[KK0 + n * 68 + kt4];
        float4 k1 = *(const float4*)&sm[KK1 + n * 68 + kt4];
        float4 v0 = *(const float4*)&sm[VV0 + n * 68 + kt4];
        float4 v1 = *(const float4*)&sm[VV1 + n * 68 + kt4];
        MHA_STEP(k0.x, k1.x, v0.x, v1.x)
        MHA_STEP(k0.y, k1.y, v0.y, v1.y)
        MHA_STEP(k0.z, k1.z, v0.z, v1.z)
        MHA_STEP(k0.w, k1.w, v0.w, v1.w)
      }
#pragma unroll
      for (int i = 0; i < 4; ++i) {
        float inv = rcp_(ps[i]);
        *(float2*)&sm[QS + (qq + 16 * i) * 10 + 2 * n] =
            make_float2(c0[i] * inv, c1[i] * inv);   // ctx over q
      }
      asm volatile("s_waitcnt lgkmcnt(0)" ::: "memory");

      // C3: out_proj of ctx row t -> stage in OCT
      {
        float2 cp0 = *(const float2*)&sm[QS + t * 10 + 0];
        float2 cp1 = *(const float2*)&sm[QS + t * 10 + 2];
        float2 cp2 = *(const float2*)&sm[QS + t * 10 + 4];
        float2 cp3 = *(const float2*)&sm[QS + t * 10 + 6];
        float cx[8] = {cp0.x, cp0.y, cp1.x, cp1.y, cp2.x, cp2.y, cp3.x, cp3.y};
        float o8[8];
#pragma unroll
        for (int jj = 0; jj < 8; ++jj) {
          float a = ob[jj];
#pragma unroll
          for (int h = 0; h < 8; ++h) a = fmaf(cx[h], ow[jj * 8 + h], a);
          o8[jj] = a;
        }
        float* od = &smem[OCT + fl * 640 + t * 10];
        *(float4*)&od[0] = make_float4(o8[0], o8[1], o8[2], o8[3]);
        *(float4*)&od[4] = make_float4(o8[4], o8[5], o8[6], o8[7]);
      }
    }
  }
  __syncthreads();

  // ---- burst attn store: per t, 8f x 8h = 256B contiguous ----
  {
#pragma unroll
    for (int i = 0; i < 4; ++i) {
      int v = i * 256 + tid;            // float4 index (1024 total)
      int t = v >> 4;
      int c = v & 15;                   // f = c>>1, h0 = (c&1)*4
      const float* sp = &smem[OCT + (c >> 1) * 640 + t * 10 + (c & 1) * 4];
      float4* dst = (float4*)(attn + ((b * Tt + t) * Ff + f0) * Hh);
      dst[c] = *(const float4*)sp;
    }
  }
}

// ---------------- K2: y = out.reshape(B,T,F*H) @ Wout^T + bout (bf16 reads) ----------------
// grid: B*(T/8) = 256 blocks, 128 threads = 8 o-quads x 16 f-chunks (R2 proven shape).
__global__ __launch_bounds__(128) void k_outproj(
    const ushort* __restrict__ outp, const float* __restrict__ Wout,
    const float* __restrict__ bout, float* __restrict__ y) {
  constexpr int TT = 8;
  int blk = blockIdx.x;
  int b = blk >> 3;
  int t0 = (blk & 7) * TT;
  int tid = threadIdx.x;
  int oq = tid >> 4;
  int fc = tid & 15;
  float acc[TT][4];
#pragma unroll
  for (int tt = 0; tt < TT; ++tt)
#pragma unroll
    for (int od = 0; od < 4; ++od) acc[tt][od] = 0.f;
#pragma unroll
  for (int ff = 0; ff < 8; ++ff) {
    int f = fc * 8 + ff;
    const uint4* rb = (const uint4*)(outp + (size_t)((b * Ff + f) * Tt + t0) * Hh);
    uint4 rq[TT];
#pragma unroll
    for (int i = 0; i < TT; ++i) rq[i] = rb[i];   // one uint4 = one t row (8 bf16)
    float4 rv[16];
#pragma unroll
    for (int tt = 0; tt < TT; ++tt) {
      uint4 q = rq[tt];
      rv[tt * 2]     = make_float4(bflo_(q.x), bfhi_(q.x), bflo_(q.y), bfhi_(q.y));
      rv[tt * 2 + 1] = make_float4(bflo_(q.z), bfhi_(q.z), bflo_(q.w), bfhi_(q.w));
    }
#pragma unroll
    for (int od = 0; od < 4; ++od) {
      int o = oq * 4 + od;
      const float4* wbp = (const float4*)(Wout + o * (Ff * Hh) + f * Hh);
      float4 wa = wbp[0], wc = wbp[1];
#pragma unroll
      for (int tt = 0; tt < TT; ++tt) {
        float4 ra = rv[tt * 2], rc = rv[tt * 2 + 1];
        float s = acc[tt][od];
        s = fmaf(ra.x, wa.x, s); s = fmaf(ra.y, wa.y, s);
        s = fmaf(ra.z, wa.z, s); s = fmaf(ra.w, wa.w, s);
        s = fmaf(rc.x, wc.x, s); s = fmaf(rc.y, wc.y, s);
        s = fmaf(rc.z, wc.z, s); s = fmaf(rc.w, wc.w, s);
        acc[tt][od] = s;
      }
    }
  }
#pragma unroll
  for (int tt = 0; tt < TT; ++tt)
#pragma unroll
    for (int od = 0; od < 4; ++od) {
      float v = acc[tt][od];
      v += __shfl_xor(v, 1, 16);
      v += __shfl_xor(v, 2, 16);
      v += __shfl_xor(v, 4, 16);
      v += __shfl_xor(v, 8, 16);
      acc[tt][od] = v;
    }
#pragma unroll
  for (int tt = 0; tt < TT; ++tt) {
    if (fc == tt) {
#pragma unroll
      for (int od = 0; od < 4; ++od) {
        int o = oq * 4 + od;
        y[(b * Tt + t0 + tt) * HIDh + o] = acc[tt][od] + bout[o];
      }
    }
  }
}

extern "C" void kernel_launch(void* const* d_in, const int* in_sizes, int n_in,
                              void* d_out, int out_size, void* d_ws, size_t ws_size,
                              hipStream_t stream) {
  (void)in_sizes; (void)n_in; (void)out_size; (void)ws_size;
  const float* x    = (const float*)d_in[0];
  const float* Wp   = (const float*)d_in[1];
  const float* bp   = (const float*)d_in[2];
  const float* W_ih = (const float*)d_in[3];
  const float* b_ih = (const float*)d_in[4];
  const float* W_hh = (const float*)d_in[5];
  const float* b_hh = (const float*)d_in[6];
  const float* in_w = (const float*)d_in[7];
  const float* in_b = (const float*)d_in[8];
  const float* ow   = (const float*)d_in[9];
  const float* ob   = (const float*)d_in[10];
  const float* Wout = (const float*)d_in[11];
  const float* bout = (const float*)d_in[12];

  float* y     = (float*)d_out;
  float* attn  = (float*)d_out + Bb * Tt * HIDh;
  ushort* outp = (ushort*)d_ws;   // B*F*T*H bf16 (4 MB)

  hipLaunchKernelGGL(k_fused, dim3(Bb * (Ff / 8)), dim3(256), 0, stream,
                     x, Wp, bp, W_ih, b_ih, W_hh, b_hh, in_w, in_b, ow, ob, outp, attn);
  hipLaunchKernelGGL(k_outproj, dim3(Bb * (Tt / 8)), dim3(128), 0, stream,
                     outp, Wout, bout, y);
}